// Round 2
// baseline (195.180 us; speedup 1.0000x reference)
//
#include <hip/hip_runtime.h>
#include <stdint.h>

#define C_DIM 512
#define NHEADS 8
#define HDIM 64
#define BATCH 8
#define NPIX 1024
#define ATTN_SCALE 0.125f

typedef __bf16 bf16x8 __attribute__((ext_vector_type(8)));
typedef float f32x4 __attribute__((ext_vector_type(4)));

__device__ __forceinline__ unsigned short f2bf(float f) {
  union { float f; unsigned u; } v; v.f = f;
  unsigned r = v.u + 0x7fffu + ((v.u >> 16) & 1u);
  return (unsigned short)(r >> 16);
}

__device__ __forceinline__ void gl_lds16(const void* g, void* l) {
  __builtin_amdgcn_global_load_lds(
      (__attribute__((address_space(1))) void*)g,
      (__attribute__((address_space(3))) void*)l,
      16, 0, 0);
}

// ---------------- weights f32 -> bf16 ----------------
__global__ __launch_bounds__(256) void k_prep(const float* __restrict__ wq,
                                              const float* __restrict__ wk,
                                              const float* __restrict__ wv,
                                              const float* __restrict__ wp,
                                              unsigned short* __restrict__ wbf) {
  const int n = C_DIM * C_DIM;
  for (int i = blockIdx.x * blockDim.x + threadIdx.x; i < 4 * n;
       i += gridDim.x * blockDim.x) {
    const float* src = (i < n) ? wq : (i < 2 * n) ? wk : (i < 3 * n) ? wv : wp;
    wbf[i] = f2bf(src[i & (n - 1)]);
  }
}

// ---------------- BN (eval) + transpose: x (B,C,N) f32 -> hbT (B,N,C) bf16 ----
__global__ __launch_bounds__(256) void k_bnT(const float* __restrict__ x,
                                             const float* __restrict__ gamma,
                                             const float* __restrict__ beta,
                                             const float* __restrict__ rmean,
                                             const float* __restrict__ rvar,
                                             unsigned short* __restrict__ hbT) {
  __shared__ unsigned short tile[64][72];
  const int b = blockIdx.z, c0 = blockIdx.y * 64, n0 = blockIdx.x * 64;
  const int t = threadIdx.x;
#pragma unroll
  for (int it = 0; it < 4; ++it) {
    int c = it * 16 + (t >> 4);
    int n = (t & 15) * 4;
    const float4 v = *(const float4*)&x[((size_t)b * C_DIM + c0 + c) * NPIX + n0 + n];
    int cc = c0 + c;
    float inv = gamma[cc] * rsqrtf(rvar[cc] + 1e-5f);
    float add = beta[cc] - rmean[cc] * inv;
    tile[c][n + 0] = f2bf(v.x * inv + add);
    tile[c][n + 1] = f2bf(v.y * inv + add);
    tile[c][n + 2] = f2bf(v.z * inv + add);
    tile[c][n + 3] = f2bf(v.w * inv + add);
  }
  __syncthreads();
#pragma unroll
  for (int it = 0; it < 2; ++it) {
    int n = it * 32 + (t >> 3);
    int cj = (t & 7) * 8;
    unsigned short tmp[8];
#pragma unroll
    for (int u = 0; u < 8; ++u) tmp[u] = tile[cj + u][n];
    uint4 pk;
    pk.x = (unsigned)tmp[0] | ((unsigned)tmp[1] << 16);
    pk.y = (unsigned)tmp[2] | ((unsigned)tmp[3] << 16);
    pk.z = (unsigned)tmp[4] | ((unsigned)tmp[5] << 16);
    pk.w = (unsigned)tmp[6] | ((unsigned)tmp[7] << 16);
    *(uint4*)&hbT[((size_t)b * NPIX + n0 + n) * C_DIM + c0 + cj] = pk;
  }
}

// ---------------- QKV GEMM: OUT[o][n] = W h + b ----------------
// A = W (O,C) bf16 row-major; B[k=c][n] = hbT[b][n][c]. Tiles 128x128, BK=32.
// Q,K stored transposed (B,N,C); V stored (B,C,N).
__global__ __launch_bounds__(256) void k_qkv(const unsigned short* __restrict__ wbf,
                                             const float* __restrict__ bq,
                                             const float* __restrict__ bk,
                                             const float* __restrict__ bv,
                                             const unsigned short* __restrict__ hbT,
                                             unsigned short* __restrict__ QT,
                                             unsigned short* __restrict__ KT,
                                             unsigned short* __restrict__ Vb) {
  __shared__ unsigned short Atile[128 * 32];
  __shared__ unsigned short Btile[128 * 32];
  const int which = blockIdx.z >> 3;
  const int b = blockIdx.z & 7;
  const int m0 = blockIdx.y * 128, n0 = blockIdx.x * 128;
  const unsigned short* W = wbf + (size_t)which * C_DIM * C_DIM;
  const int t = threadIdx.x, wave = t >> 6, lane = t & 63;
  const int wr = wave >> 1, wc = wave & 1;
  f32x4 acc[4][4] = {};

  // swizzled staging source column: phys_blk = lane&3, row = q*16 + (lane>>2)
  const int st_row = lane >> 2;
  const int st_col = (((lane & 3) ^ ((lane >> 3) & 3))) * 8;

  for (int k0 = 0; k0 < C_DIM; k0 += 32) {
    __syncthreads();
#pragma unroll
    for (int it = 0; it < 2; ++it) {
      int q = wave + 4 * it;
      int row = q * 16 + st_row;
      gl_lds16(&W[(size_t)(m0 + row) * C_DIM + k0 + st_col], &Atile[q * 512]);
      gl_lds16(&hbT[((size_t)b * NPIX + n0 + row) * C_DIM + k0 + st_col], &Btile[q * 512]);
    }
    __syncthreads();
    bf16x8 af[4], bfr[4];
#pragma unroll
    for (int i = 0; i < 4; ++i) {
      int row = wr * 64 + i * 16 + (lane & 15);
      af[i] = *(const bf16x8*)&Atile[row * 32 + (((lane >> 4) ^ ((row >> 1) & 3)) * 8)];
    }
#pragma unroll
    for (int j = 0; j < 4; ++j) {
      int row = wc * 64 + j * 16 + (lane & 15);
      bfr[j] = *(const bf16x8*)&Btile[row * 32 + (((lane >> 4) ^ ((row >> 1) & 3)) * 8)];
    }
#pragma unroll
    for (int i = 0; i < 4; ++i)
#pragma unroll
      for (int j = 0; j < 4; ++j)
        acc[i][j] = __builtin_amdgcn_mfma_f32_16x16x32_bf16(af[i], bfr[j], acc[i][j], 0, 0, 0);
  }

  const float* bias = (which == 0) ? bq : (which == 1) ? bk : bv;
  if (which < 2) {
    unsigned short* T = (which == 0) ? QT : KT;
#pragma unroll
    for (int i = 0; i < 4; ++i) {
      int o = m0 + wr * 64 + i * 16 + (lane >> 4) * 4;
      float b0 = bias[o + 0], b1 = bias[o + 1], b2 = bias[o + 2], b3 = bias[o + 3];
#pragma unroll
      for (int j = 0; j < 4; ++j) {
        int n = n0 + wc * 64 + j * 16 + (lane & 15);
        ushort4 pk;
        pk.x = f2bf(acc[i][j][0] + b0);
        pk.y = f2bf(acc[i][j][1] + b1);
        pk.z = f2bf(acc[i][j][2] + b2);
        pk.w = f2bf(acc[i][j][3] + b3);
        *(ushort4*)&T[((size_t)b * NPIX + n) * C_DIM + o] = pk;
      }
    }
  } else {
#pragma unroll
    for (int i = 0; i < 4; ++i) {
      int o = m0 + wr * 64 + i * 16 + (lane >> 4) * 4;
#pragma unroll
      for (int j = 0; j < 4; ++j) {
        int n = n0 + wc * 64 + j * 16 + (lane & 15);
#pragma unroll
        for (int r = 0; r < 4; ++r)
          Vb[((size_t)b * C_DIM + o + r) * NPIX + n] = f2bf(acc[i][j][r] + bias[o + r]);
      }
    }
  }
}

// ---------------- attention: per (b,h,128-row q-tile) ----------------
__global__ __launch_bounds__(256) void k_attn(const unsigned short* __restrict__ QT,
                                              const unsigned short* __restrict__ KT,
                                              const unsigned short* __restrict__ Vb,
                                              unsigned short* __restrict__ AOT) {
  __shared__ unsigned short Qs[128 * 64];
  __shared__ unsigned short Ks[128 * 64];
  __shared__ unsigned short Vs[64 * 128];
  __shared__ unsigned short Ps[4][32 * 136];
  __shared__ float rs_lds[128];

  const int b = blockIdx.z, h = blockIdx.y, n0 = blockIdx.x * 128;
  const int t = threadIdx.x, wave = t >> 6, lane = t & 63;

  // Q/K staging swizzle: row = q*8 + (lane>>3); col = ((lane&7) ^ (lane>>3))*8
  const int qk_row = lane >> 3;
  const int qk_col = ((lane & 7) ^ (lane >> 3)) * 8;

#pragma unroll
  for (int it = 0; it < 4; ++it) {
    int q = wave + 4 * it;
    gl_lds16(&QT[((size_t)b * NPIX + n0 + q * 8 + qk_row) * C_DIM + h * HDIM + qk_col],
             &Qs[q * 512]);
  }

  f32x4 oacc[2][4] = {};
  float rsum[2][4] = {};

  for (int m0 = 0; m0 < NPIX; m0 += 128) {
    __syncthreads();
#pragma unroll
    for (int it = 0; it < 4; ++it) {
      int q = wave + 4 * it;
      gl_lds16(&KT[((size_t)b * NPIX + m0 + q * 8 + qk_row) * C_DIM + h * HDIM + qk_col],
               &Ks[q * 512]);
    }
#pragma unroll
    for (int it = 0; it < 4; ++it) {
      int q = wave + 4 * it;
      int row = q * 4 + (lane >> 4);
      int col = ((lane & 15) ^ (((q & 1) * 4) + (lane >> 4))) * 8;
      gl_lds16(&Vb[((size_t)b * C_DIM + h * HDIM + row) * NPIX + m0 + col], &Vs[q * 512]);
    }
    __syncthreads();

    // S = Q^T K (this wave: 32 q-rows x 128 k-cols)
    f32x4 s[2][8] = {};
#pragma unroll
    for (int kk = 0; kk < 2; ++kk) {
      bf16x8 aq[2], bk8[8];
#pragma unroll
      for (int i = 0; i < 2; ++i) {
        int row = wave * 32 + i * 16 + (lane & 15);
        aq[i] = *(const bf16x8*)&Qs[row * 64 + (((kk * 4 + (lane >> 4)) ^ (row & 7)) * 8)];
      }
#pragma unroll
      for (int j = 0; j < 8; ++j) {
        int row = j * 16 + (lane & 15);
        bk8[j] = *(const bf16x8*)&Ks[row * 64 + (((kk * 4 + (lane >> 4)) ^ (row & 7)) * 8)];
      }
#pragma unroll
      for (int i = 0; i < 2; ++i)
#pragma unroll
        for (int j = 0; j < 8; ++j)
          s[i][j] = __builtin_amdgcn_mfma_f32_16x16x32_bf16(aq[i], bk8[j], s[i][j], 0, 0, 0);
    }

    // P = exp(clip(S*scale)); accumulate rowsum; stage P (bf16) per-wave
#pragma unroll
    for (int i = 0; i < 2; ++i)
#pragma unroll
      for (int j = 0; j < 8; ++j)
#pragma unroll
        for (int r = 0; r < 4; ++r) {
          float e = __expf(fminf(fmaxf(s[i][j][r] * ATTN_SCALE, -50.f), 50.f));
          rsum[i][r] += e;
          Ps[wave][(i * 16 + (lane >> 4) * 4 + r) * 136 + j * 16 + (lane & 15)] = f2bf(e);
        }
    __syncthreads();

    // O^T += V * P^T  (rows d=64, cols = wave's 32 q-rows)
#pragma unroll
    for (int kk = 0; kk < 4; ++kk) {
      bf16x8 av[4], bp8[2];
#pragma unroll
      for (int dj = 0; dj < 4; ++dj) {
        int row = dj * 16 + (lane & 15);
        av[dj] = *(const bf16x8*)&Vs[row * 128 + (((kk * 4 + (lane >> 4)) ^ (row & 7)) * 8)];
      }
#pragma unroll
      for (int ai = 0; ai < 2; ++ai)
        bp8[ai] = *(const bf16x8*)&Ps[wave][(ai * 16 + (lane & 15)) * 136 + kk * 32 + (lane >> 4) * 8];
#pragma unroll
      for (int ai = 0; ai < 2; ++ai)
#pragma unroll
        for (int dj = 0; dj < 4; ++dj)
          oacc[ai][dj] = __builtin_amdgcn_mfma_f32_16x16x32_bf16(av[dj], bp8[ai], oacc[ai][dj], 0, 0, 0);
    }
  }

  // rowsum: butterfly across the 16-lane group
#pragma unroll
  for (int i = 0; i < 2; ++i)
#pragma unroll
    for (int r = 0; r < 4; ++r) {
      float v = rsum[i][r];
      v += __shfl_xor(v, 1);
      v += __shfl_xor(v, 2);
      v += __shfl_xor(v, 4);
      v += __shfl_xor(v, 8);
      rsum[i][r] = v;
    }
  if ((lane & 15) == 0) {
#pragma unroll
    for (int i = 0; i < 2; ++i)
#pragma unroll
      for (int r = 0; r < 4; ++r)
        rs_lds[wave * 32 + i * 16 + (lane >> 4) * 4 + r] = rsum[i][r];
  }
  __syncthreads();

#pragma unroll
  for (int ai = 0; ai < 2; ++ai) {
    float inv = 1.0f / rs_lds[wave * 32 + ai * 16 + (lane & 15)];
    int n = n0 + wave * 32 + ai * 16 + (lane & 15);
#pragma unroll
    for (int dj = 0; dj < 4; ++dj) {
      ushort4 pk;
      pk.x = f2bf(oacc[ai][dj][0] * inv);
      pk.y = f2bf(oacc[ai][dj][1] * inv);
      pk.z = f2bf(oacc[ai][dj][2] * inv);
      pk.w = f2bf(oacc[ai][dj][3] * inv);
      *(ushort4*)&AOT[((size_t)b * NPIX + n) * C_DIM + h * HDIM + dj * 16 + (lane >> 4) * 4] = pk;
    }
  }
}

// ---------------- proj GEMM + bias + residual (f32 out) ----------------
__global__ __launch_bounds__(256) void k_proj(const unsigned short* __restrict__ Wp,
                                              const float* __restrict__ bp,
                                              const unsigned short* __restrict__ AOT,
                                              const float* __restrict__ x,
                                              float* __restrict__ out) {
  __shared__ unsigned short Atile[128 * 32];
  __shared__ unsigned short Btile[128 * 32];
  const int b = blockIdx.z;
  const int m0 = blockIdx.y * 128, n0 = blockIdx.x * 128;
  const int t = threadIdx.x, wave = t >> 6, lane = t & 63;
  const int wr = wave >> 1, wc = wave & 1;
  f32x4 acc[4][4] = {};
  const int st_row = lane >> 2;
  const int st_col = (((lane & 3) ^ ((lane >> 3) & 3))) * 8;

  for (int k0 = 0; k0 < C_DIM; k0 += 32) {
    __syncthreads();
#pragma unroll
    for (int it = 0; it < 2; ++it) {
      int q = wave + 4 * it;
      int row = q * 16 + st_row;
      gl_lds16(&Wp[(size_t)(m0 + row) * C_DIM + k0 + st_col], &Atile[q * 512]);
      gl_lds16(&AOT[((size_t)b * NPIX + n0 + row) * C_DIM + k0 + st_col], &Btile[q * 512]);
    }
    __syncthreads();
    bf16x8 af[4], bfr[4];
#pragma unroll
    for (int i = 0; i < 4; ++i) {
      int row = wr * 64 + i * 16 + (lane & 15);
      af[i] = *(const bf16x8*)&Atile[row * 32 + (((lane >> 4) ^ ((row >> 1) & 3)) * 8)];
    }
#pragma unroll
    for (int j = 0; j < 4; ++j) {
      int row = wc * 64 + j * 16 + (lane & 15);
      bfr[j] = *(const bf16x8*)&Btile[row * 32 + (((lane >> 4) ^ ((row >> 1) & 3)) * 8)];
    }
#pragma unroll
    for (int i = 0; i < 4; ++i)
#pragma unroll
      for (int j = 0; j < 4; ++j)
        acc[i][j] = __builtin_amdgcn_mfma_f32_16x16x32_bf16(af[i], bfr[j], acc[i][j], 0, 0, 0);
  }

#pragma unroll
  for (int i = 0; i < 4; ++i) {
    int o = m0 + wr * 64 + i * 16 + (lane >> 4) * 4;
    float b0 = bp[o + 0], b1 = bp[o + 1], b2 = bp[o + 2], b3 = bp[o + 3];
#pragma unroll
    for (int j = 0; j < 4; ++j) {
      int n = n0 + wc * 64 + j * 16 + (lane & 15);
      size_t base = ((size_t)b * C_DIM + o) * NPIX + n;
      out[base + 0 * NPIX] = acc[i][j][0] + b0 + x[base + 0 * NPIX];
      out[base + 1 * NPIX] = acc[i][j][1] + b1 + x[base + 1 * NPIX];
      out[base + 2 * NPIX] = acc[i][j][2] + b2 + x[base + 2 * NPIX];
      out[base + 3 * NPIX] = acc[i][j][3] + b3 + x[base + 3 * NPIX];
    }
  }
}

extern "C" void kernel_launch(void* const* d_in, const int* in_sizes, int n_in,
                              void* d_out, int out_size, void* d_ws, size_t ws_size,
                              hipStream_t stream) {
  (void)in_sizes; (void)n_in; (void)out_size; (void)ws_size;
  const float* x     = (const float*)d_in[0];
  const float* gamma = (const float*)d_in[1];
  const float* beta  = (const float*)d_in[2];
  const float* rmean = (const float*)d_in[3];
  const float* rvar  = (const float*)d_in[4];
  const float* wq    = (const float*)d_in[5];
  const float* bq    = (const float*)d_in[6];
  const float* wk    = (const float*)d_in[7];
  const float* bk    = (const float*)d_in[8];
  const float* wv    = (const float*)d_in[9];
  const float* bv    = (const float*)d_in[10];
  const float* wp    = (const float*)d_in[11];
  const float* bp    = (const float*)d_in[12];

  unsigned short* ws  = (unsigned short*)d_ws;
  const size_t WSZ    = (size_t)C_DIM * C_DIM;        // 262144
  const size_t BIG    = (size_t)BATCH * NPIX * C_DIM; // 4194304
  unsigned short* wbf = ws;                  // 4*WSZ
  unsigned short* hbT = wbf + 4 * WSZ;
  unsigned short* QT  = hbT + BIG;
  unsigned short* KT  = QT + BIG;
  unsigned short* Vb  = KT + BIG;
  unsigned short* AOT = Vb + BIG;

  k_prep<<<dim3(512), dim3(256), 0, stream>>>(wq, wk, wv, wp, wbf);
  k_bnT<<<dim3(16, 8, 8), dim3(256), 0, stream>>>(x, gamma, beta, rmean, rvar, hbT);
  k_qkv<<<dim3(8, 4, 24), dim3(256), 0, stream>>>(wbf, bq, bk, bv, hbT, QT, KT, Vb);
  k_attn<<<dim3(8, 8, 8), dim3(256), 0, stream>>>(QT, KT, Vb, AOT);
  k_proj<<<dim3(8, 4, 8), dim3(256), 0, stream>>>(wbf + 3 * WSZ, bp, AOT, x, (float*)d_out);
}

// Round 4
// 173.427 us; speedup vs baseline: 1.1254x; 1.1254x over previous
//
#include <hip/hip_runtime.h>
#include <stdint.h>

#define C_DIM 512
#define NHEADS 8
#define HDIM 64
#define BATCH 8
#define NPIX 1024
// Q pre-scale: (1/sqrt(64)) * log2(e) -> exp becomes bare exp2
#define Q_PRESCALE 0.18033688011112042f
// clip +-50 in exp-space -> +-50*log2(e) in exp2-space
#define CLIP_LOG2 72.13475204444817f

typedef __bf16 bf16x8 __attribute__((ext_vector_type(8)));
typedef float f32x4 __attribute__((ext_vector_type(4)));
typedef float f32x16 __attribute__((ext_vector_type(16)));

__device__ __forceinline__ unsigned short f2bf(float f) {
  union { float f; unsigned u; } v; v.f = f;
  unsigned r = v.u + 0x7fffu + ((v.u >> 16) & 1u);
  return (unsigned short)(r >> 16);
}

__device__ __forceinline__ void gl_lds16(const void* g, void* l) {
  __builtin_amdgcn_global_load_lds(
      (__attribute__((address_space(1))) void*)g,
      (__attribute__((address_space(3))) void*)l,
      16, 0, 0);
}

// ---------------- weights f32 -> bf16 ----------------
__global__ __launch_bounds__(256) void k_prep(const float* __restrict__ wq,
                                              const float* __restrict__ wk,
                                              const float* __restrict__ wv,
                                              const float* __restrict__ wp,
                                              unsigned short* __restrict__ wbf) {
  const int n = C_DIM * C_DIM;
  for (int i = blockIdx.x * blockDim.x + threadIdx.x; i < 4 * n;
       i += gridDim.x * blockDim.x) {
    const float* src = (i < n) ? wq : (i < 2 * n) ? wk : (i < 3 * n) ? wv : wp;
    wbf[i] = f2bf(src[i & (n - 1)]);
  }
}

// ---------------- BN (eval) + transpose: x (B,C,N) f32 -> hbT (B,N,C) bf16 ----
__global__ __launch_bounds__(256) void k_bnT(const float* __restrict__ x,
                                             const float* __restrict__ gamma,
                                             const float* __restrict__ beta,
                                             const float* __restrict__ rmean,
                                             const float* __restrict__ rvar,
                                             unsigned short* __restrict__ hbT) {
  __shared__ unsigned short tile[64][72];
  const int b = blockIdx.z, c0 = blockIdx.y * 64, n0 = blockIdx.x * 64;
  const int t = threadIdx.x;
#pragma unroll
  for (int it = 0; it < 4; ++it) {
    int c = it * 16 + (t >> 4);
    int n = (t & 15) * 4;
    const float4 v = *(const float4*)&x[((size_t)b * C_DIM + c0 + c) * NPIX + n0 + n];
    int cc = c0 + c;
    float inv = gamma[cc] * rsqrtf(rvar[cc] + 1e-5f);
    float add = beta[cc] - rmean[cc] * inv;
    tile[c][n + 0] = f2bf(v.x * inv + add);
    tile[c][n + 1] = f2bf(v.y * inv + add);
    tile[c][n + 2] = f2bf(v.z * inv + add);
    tile[c][n + 3] = f2bf(v.w * inv + add);
  }
  __syncthreads();
#pragma unroll
  for (int it = 0; it < 2; ++it) {
    int n = it * 32 + (t >> 3);
    int cj = (t & 7) * 8;
    unsigned short tmp[8];
#pragma unroll
    for (int u = 0; u < 8; ++u) tmp[u] = tile[cj + u][n];
    uint4 pk;
    pk.x = (unsigned)tmp[0] | ((unsigned)tmp[1] << 16);
    pk.y = (unsigned)tmp[2] | ((unsigned)tmp[3] << 16);
    pk.z = (unsigned)tmp[4] | ((unsigned)tmp[5] << 16);
    pk.w = (unsigned)tmp[6] | ((unsigned)tmp[7] << 16);
    *(uint4*)&hbT[((size_t)b * NPIX + n0 + n) * C_DIM + c0 + cj] = pk;
  }
}

// ---------------- QKV GEMM: OUT[o][n] = W h + b ----------------
// Q,K stored transposed (B,N,C); V stored (B,C,N). Q pre-scaled by Q_PRESCALE.
__global__ __launch_bounds__(256) void k_qkv(const unsigned short* __restrict__ wbf,
                                             const float* __restrict__ bq,
                                             const float* __restrict__ bk,
                                             const float* __restrict__ bv,
                                             const unsigned short* __restrict__ hbT,
                                             unsigned short* __restrict__ QT,
                                             unsigned short* __restrict__ KT,
                                             unsigned short* __restrict__ Vb) {
  __shared__ unsigned short Atile[128 * 32];
  __shared__ unsigned short Btile[128 * 32];
  const int which = blockIdx.z >> 3;
  const int b = blockIdx.z & 7;
  const int m0 = blockIdx.y * 128, n0 = blockIdx.x * 128;
  const unsigned short* W = wbf + (size_t)which * C_DIM * C_DIM;
  const int t = threadIdx.x, wave = t >> 6, lane = t & 63;
  const int wr = wave >> 1, wc = wave & 1;
  f32x4 acc[4][4] = {};

  const int st_row = lane >> 2;
  const int st_col = (((lane & 3) ^ ((lane >> 3) & 3))) * 8;

  for (int k0 = 0; k0 < C_DIM; k0 += 32) {
    __syncthreads();
#pragma unroll
    for (int it = 0; it < 2; ++it) {
      int q = wave + 4 * it;
      int row = q * 16 + st_row;
      gl_lds16(&W[(size_t)(m0 + row) * C_DIM + k0 + st_col], &Atile[q * 512]);
      gl_lds16(&hbT[((size_t)b * NPIX + n0 + row) * C_DIM + k0 + st_col], &Btile[q * 512]);
    }
    __syncthreads();
    bf16x8 af[4], bfr[4];
#pragma unroll
    for (int i = 0; i < 4; ++i) {
      int row = wr * 64 + i * 16 + (lane & 15);
      af[i] = *(const bf16x8*)&Atile[row * 32 + (((lane >> 4) ^ ((row >> 1) & 3)) * 8)];
    }
#pragma unroll
    for (int j = 0; j < 4; ++j) {
      int row = wc * 64 + j * 16 + (lane & 15);
      bfr[j] = *(const bf16x8*)&Btile[row * 32 + (((lane >> 4) ^ ((row >> 1) & 3)) * 8)];
    }
#pragma unroll
    for (int i = 0; i < 4; ++i)
#pragma unroll
      for (int j = 0; j < 4; ++j)
        acc[i][j] = __builtin_amdgcn_mfma_f32_16x16x32_bf16(af[i], bfr[j], acc[i][j], 0, 0, 0);
  }

  const float* bias = (which == 0) ? bq : (which == 1) ? bk : bv;
  if (which < 2) {
    unsigned short* T = (which == 0) ? QT : KT;
    const float qs = (which == 0) ? Q_PRESCALE : 1.0f;
#pragma unroll
    for (int i = 0; i < 4; ++i) {
      int o = m0 + wr * 64 + i * 16 + (lane >> 4) * 4;
      float b0 = bias[o + 0], b1 = bias[o + 1], b2 = bias[o + 2], b3 = bias[o + 3];
#pragma unroll
      for (int j = 0; j < 4; ++j) {
        int n = n0 + wc * 64 + j * 16 + (lane & 15);
        ushort4 pk;
        pk.x = f2bf((acc[i][j][0] + b0) * qs);
        pk.y = f2bf((acc[i][j][1] + b1) * qs);
        pk.z = f2bf((acc[i][j][2] + b2) * qs);
        pk.w = f2bf((acc[i][j][3] + b3) * qs);
        *(ushort4*)&T[((size_t)b * NPIX + n) * C_DIM + o] = pk;
      }
    }
  } else {
#pragma unroll
    for (int i = 0; i < 4; ++i) {
      int o = m0 + wr * 64 + i * 16 + (lane >> 4) * 4;
#pragma unroll
      for (int j = 0; j < 4; ++j) {
        int n = n0 + wc * 64 + j * 16 + (lane & 15);
#pragma unroll
        for (int r = 0; r < 4; ++r)
          Vb[((size_t)b * C_DIM + o + r) * NPIX + n] = f2bf(acc[i][j][r] + bias[o + r]);
      }
    }
  }
}

// ---------------- attention v2: swapped QK^T, in-register P, 32x32 MFMA ----
// Block: 4 waves x 32 q-rows = 128 q. Grid 512 (1D): b=bid&7, h=(bid>>3)&7,
// qt=bid>>6 (XCD round-robin groups same-b blocks on one XCD's L2).
__global__ __launch_bounds__(256) void k_attn(const unsigned short* __restrict__ QT,
                                              const unsigned short* __restrict__ KT,
                                              const unsigned short* __restrict__ Vb,
                                              unsigned short* __restrict__ AOT) {
  __shared__ unsigned short Ks[2][128 * 64];   // [kpix][c], col-block ^= (row&7)
  __shared__ unsigned short Vs[2][64 * 128];   // [d][kpix], k-block  ^= (d&7)
  __shared__ float rs_lds[128];

  const int bid = blockIdx.x;
  const int b = bid & 7, h = (bid >> 3) & 7, qt = bid >> 6;
  const int n0 = qt * 128;
  const int lane = threadIdx.x & 63, wave = threadIdx.x >> 6;
  const int l31 = lane & 31, hi = lane >> 5;

  // Hoist Q fragments (B-operand: col q = l31, k = c). 4 chunks of c.
  bf16x8 qf[4];
  {
    const unsigned short* qbase =
        QT + ((size_t)b * NPIX + n0 + wave * 32 + l31) * C_DIM + h * HDIM + hi * 8;
#pragma unroll
    for (int kk = 0; kk < 4; ++kk) qf[kk] = *(const bf16x8*)(qbase + kk * 16);
  }

  auto stage = [&](int buf, int tile) {
    const int m0 = tile * 128;
#pragma unroll
    for (int it = 0; it < 4; ++it) {
      int rb = it * 32 + wave * 8;
      int row = rb + (lane >> 3);
      int srcc = ((lane & 7) ^ (row & 7)) * 8;
      gl_lds16(&KT[((size_t)b * NPIX + m0 + row) * C_DIM + h * HDIM + srcc],
               &Ks[buf][rb * 64]);
    }
#pragma unroll
    for (int it = 0; it < 4; ++it) {
      int rb = it * 16 + wave * 4;
      int d = rb + (lane >> 4);
      int srck = ((lane & 15) ^ (d & 7)) * 8;
      gl_lds16(&Vb[((size_t)b * C_DIM + h * HDIM + d) * NPIX + m0 + srck],
               &Vs[buf][rb * 128]);
    }
  };

  f32x16 oacc[2] = {};
  float rs0 = 0.f, rs1 = 0.f;

  stage(0, 0);
  __syncthreads();

  for (int tile = 0; tile < 8; ++tile) {
    const int cur = tile & 1;
    if (tile < 7) stage(cur ^ 1, tile + 1);

#pragma unroll
    for (int kt = 0; kt < 4; ++kt) {
      // S^T tile: A = K [32 kpix x 16 c], B = Q [16 c x 32 q]
      f32x16 s = {};
#pragma unroll
      for (int kk = 0; kk < 4; ++kk) {
        int row = kt * 32 + l31;
        int phys = (kk * 2 + hi) ^ (row & 7);
        bf16x8 kf = *(const bf16x8*)&Ks[cur][row * 64 + phys * 8];
        s = __builtin_amdgcn_mfma_f32_32x32x16_bf16(kf, qf[kk], s, 0, 0, 0);
      }
      // P = 2^med3(s) (Q pre-scaled by 0.125*log2e); pack to bf16; rowsum.
      unsigned w[8];
#pragma unroll
      for (int r2 = 0; r2 < 8; ++r2) {
        float e0 = exp2f(fminf(fmaxf(s[2 * r2], -CLIP_LOG2), CLIP_LOG2));
        float e1 = exp2f(fminf(fmaxf(s[2 * r2 + 1], -CLIP_LOG2), CLIP_LOG2));
        rs0 += e0;
        rs1 += e1;
        asm("v_cvt_pk_bf16_f32 %0, %1, %2" : "=v"(w[r2]) : "v"(e0), "v"(e1));
      }
      // Redistribute halves so each lane holds A-operand rows (k 8-blocks).
      asm volatile("v_permlane32_swap_b32 %0, %1" : "+v"(w[0]), "+v"(w[2]));
      asm volatile("v_permlane32_swap_b32 %0, %1" : "+v"(w[1]), "+v"(w[3]));
      asm volatile("v_permlane32_swap_b32 %0, %1" : "+v"(w[4]), "+v"(w[6]));
      asm volatile("v_permlane32_swap_b32 %0, %1" : "+v"(w[5]), "+v"(w[7]));
      union U8 { unsigned u[4]; bf16x8 v; };
      U8 pa0, pa1;
      pa0.u[0] = w[0]; pa0.u[1] = w[1]; pa0.u[2] = w[2]; pa0.u[3] = w[3];
      pa1.u[0] = w[4]; pa1.u[1] = w[5]; pa1.u[2] = w[6]; pa1.u[3] = w[7];
      // PV: O[q][d] += P[q][k] * V[d][k];  B-frag = Vs[d][k] (8 consecutive k)
#pragma unroll
      for (int dt = 0; dt < 2; ++dt) {
        int d = dt * 32 + l31;
        bf16x8 v0 = *(const bf16x8*)&Vs[cur][d * 128 + (((kt * 4 + hi) ^ (d & 7)) * 8)];
        bf16x8 v1 = *(const bf16x8*)&Vs[cur][d * 128 + (((kt * 4 + 2 + hi) ^ (d & 7)) * 8)];
        oacc[dt] = __builtin_amdgcn_mfma_f32_32x32x16_bf16(pa0.v, v0, oacc[dt], 0, 0, 0);
        oacc[dt] = __builtin_amdgcn_mfma_f32_32x32x16_bf16(pa1.v, v1, oacc[dt], 0, 0, 0);
      }
    }
    __syncthreads();
  }

  // Row sums: lane l and l+32 hold disjoint k-subsets of column q=l31.
  float tot = rs0 + rs1;
  tot += __shfl_xor(tot, 32);
  if (lane < 32) rs_lds[wave * 32 + lane] = tot;

  float inv[16];
#pragma unroll
  for (int r = 0; r < 16; ++r)
    inv[r] = 1.0f / rs_lds[wave * 32 + (r & 3) + 8 * (r >> 2) + 4 * hi];

  __bf16* obase = (__bf16*)(AOT + ((size_t)b * NPIX + n0 + wave * 32) * C_DIM +
                            h * HDIM + l31);
#pragma unroll
  for (int dt = 0; dt < 2; ++dt)
#pragma unroll
    for (int r = 0; r < 16; ++r) {
      int q = (r & 3) + 8 * (r >> 2) + 4 * hi;
      obase[(size_t)q * C_DIM + dt * 32] = (__bf16)(oacc[dt][r] * inv[r]);
    }
}

// ---------------- proj GEMM + bias + residual (f32 out) ----------------
__global__ __launch_bounds__(256) void k_proj(const unsigned short* __restrict__ Wp,
                                              const float* __restrict__ bp,
                                              const unsigned short* __restrict__ AOT,
                                              const float* __restrict__ x,
                                              float* __restrict__ out) {
  __shared__ unsigned short Atile[128 * 32];
  __shared__ unsigned short Btile[128 * 32];
  const int b = blockIdx.z;
  const int m0 = blockIdx.y * 128, n0 = blockIdx.x * 128;
  const int t = threadIdx.x, wave = t >> 6, lane = t & 63;
  const int wr = wave >> 1, wc = wave & 1;
  f32x4 acc[4][4] = {};
  const int st_row = lane >> 2;
  const int st_col = (((lane & 3) ^ ((lane >> 3) & 3))) * 8;

  for (int k0 = 0; k0 < C_DIM; k0 += 32) {
    __syncthreads();
#pragma unroll
    for (int it = 0; it < 2; ++it) {
      int q = wave + 4 * it;
      int row = q * 16 + st_row;
      gl_lds16(&Wp[(size_t)(m0 + row) * C_DIM + k0 + st_col], &Atile[q * 512]);
      gl_lds16(&AOT[((size_t)b * NPIX + n0 + row) * C_DIM + k0 + st_col], &Btile[q * 512]);
    }
    __syncthreads();
    bf16x8 af[4], bfr[4];
#pragma unroll
    for (int i = 0; i < 4; ++i) {
      int row = wr * 64 + i * 16 + (lane & 15);
      af[i] = *(const bf16x8*)&Atile[row * 32 + (((lane >> 4) ^ ((row >> 1) & 3)) * 8)];
    }
#pragma unroll
    for (int j = 0; j < 4; ++j) {
      int row = wc * 64 + j * 16 + (lane & 15);
      bfr[j] = *(const bf16x8*)&Btile[row * 32 + (((lane >> 4) ^ ((row >> 1) & 3)) * 8)];
    }
#pragma unroll
    for (int i = 0; i < 4; ++i)
#pragma unroll
      for (int j = 0; j < 4; ++j)
        acc[i][j] = __builtin_amdgcn_mfma_f32_16x16x32_bf16(af[i], bfr[j], acc[i][j], 0, 0, 0);
  }

#pragma unroll
  for (int i = 0; i < 4; ++i) {
    int o = m0 + wr * 64 + i * 16 + (lane >> 4) * 4;
    float b0 = bp[o + 0], b1 = bp[o + 1], b2 = bp[o + 2], b3 = bp[o + 3];
#pragma unroll
    for (int j = 0; j < 4; ++j) {
      int n = n0 + wc * 64 + j * 16 + (lane & 15);
      size_t base = ((size_t)b * C_DIM + o) * NPIX + n;
      out[base + 0 * NPIX] = acc[i][j][0] + b0 + x[base + 0 * NPIX];
      out[base + 1 * NPIX] = acc[i][j][1] + b1 + x[base + 1 * NPIX];
      out[base + 2 * NPIX] = acc[i][j][2] + b2 + x[base + 2 * NPIX];
      out[base + 3 * NPIX] = acc[i][j][3] + b3 + x[base + 3 * NPIX];
    }
  }
}

extern "C" void kernel_launch(void* const* d_in, const int* in_sizes, int n_in,
                              void* d_out, int out_size, void* d_ws, size_t ws_size,
                              hipStream_t stream) {
  (void)in_sizes; (void)n_in; (void)out_size; (void)ws_size;
  const float* x     = (const float*)d_in[0];
  const float* gamma = (const float*)d_in[1];
  const float* beta  = (const float*)d_in[2];
  const float* rmean = (const float*)d_in[3];
  const float* rvar  = (const float*)d_in[4];
  const float* wq    = (const float*)d_in[5];
  const float* bq    = (const float*)d_in[6];
  const float* wk    = (const float*)d_in[7];
  const float* bk    = (const float*)d_in[8];
  const float* wv    = (const float*)d_in[9];
  const float* bv    = (const float*)d_in[10];
  const float* wp    = (const float*)d_in[11];
  const float* bp    = (const float*)d_in[12];

  unsigned short* ws  = (unsigned short*)d_ws;
  const size_t WSZ    = (size_t)C_DIM * C_DIM;        // 262144
  const size_t BIG    = (size_t)BATCH * NPIX * C_DIM; // 4194304
  unsigned short* wbf = ws;                  // 4*WSZ
  unsigned short* hbT = wbf + 4 * WSZ;
  unsigned short* QT  = hbT + BIG;
  unsigned short* KT  = QT + BIG;
  unsigned short* Vb  = KT + BIG;
  unsigned short* AOT = Vb + BIG;

  k_prep<<<dim3(512), dim3(256), 0, stream>>>(wq, wk, wv, wp, wbf);
  k_bnT<<<dim3(16, 8, 8), dim3(256), 0, stream>>>(x, gamma, beta, rmean, rvar, hbT);
  k_qkv<<<dim3(8, 4, 24), dim3(256), 0, stream>>>(wbf, bq, bk, bv, hbT, QT, KT, Vb);
  k_attn<<<dim3(512), dim3(256), 0, stream>>>(QT, KT, Vb, AOT);
  k_proj<<<dim3(8, 4, 8), dim3(256), 0, stream>>>(wbf + 3 * WSZ, bp, AOT, x, (float*)d_out);
}